// Round 12
// baseline (145.829 us; speedup 1.0000x reference)
//
#include <hip/hip_runtime.h>
#include <math.h>

typedef _Float16 h2_t __attribute__((ext_vector_type(2)));
typedef _Float16 h4_t __attribute__((ext_vector_type(4)));
typedef _Float16 h8_t __attribute__((ext_vector_type(8)));

#define NP 32
#define KC 31
#define HH 512
#define WW 512
#define BB 4
#define CC 3

#define TXO 32
#define TYO 32
#define TROWS 62      // 32 outputs + 15 + 15 halo
#define TWORDS 48     // tile row STRIDE in half2-words (%32==16 -> conflict-free, 1.0e6 measured)
#define TLW 32        // words STAGED per row (reads touch words 0..31 only)
#define WSTR 36       // weight table plane stride in half2-words

// Packed per-plane 1D Gaussian taps, phase A = (g[2m],g[2m+1]), phase B = (g[2m-1],g[2m]).
// HARD CONSTRAINTS (measured): weight gen stays in this separate kernel (R4);
// grid z stays BB (R4/R5: z=12 -> GB-scale scratch traffic); tiles don't shrink
// (R7); >128 VGPRs unobtainable -> 4 outputs/thread (R9/R10 spilled); keep the
// R6 insert-style unpack (R11's explicit shufflevector regressed 20%).
__device__ h2_t g_wtabh[NP * WSTR];

__global__ void init_wtab_kernel() {
    const int tid = threadIdx.x;          // 0..1023
    const int p = tid >> 5;               // plane
    const int t = tid & 31;               // padded tap position 0..31 (g[31]==0)
    const double stepd = 50.0 / 31.0;
    double coc = (p < 31) ? (double)p * stepd : 50.0;   // numpy linspace semantics
    float gt;
    if (coc < 0.5) {
        gt = (t == 15) ? 1.f : 0.f;       // identity plane (plane 0 only)
    } else {
        double sigma = coc / 2.355;
        int k = (int)(2.0 * coc + 1.0);   // trunc, matches python int()
        if ((k & 1) == 0) k += 1;
        if (k > KC) k = KC;
        int h = k / 2;
        int d = t - 15;
        float denom = (float)(2.0 * sigma * sigma);
        float v = (d >= -h && d <= h && t < KC) ? expf(-(float)(d * d) / denom) : 0.f;
        float s = v;
        #pragma unroll
        for (int off = 1; off < 32; off <<= 1) s += __shfl_xor(s, off, 32);
        gt = v / s;
    }
    const int m = t & 15;
    const int s0 = (t < 16) ? (2 * m) : ((2 * m - 1 < 0) ? 0 : 2 * m - 1);
    const int s1 = (t < 16) ? (2 * m + 1) : (2 * m);
    float w0 = __shfl(gt, s0, 32);
    float w1 = __shfl(gt, s1, 32);
    if (t >= 16 && (2 * m - 1) < 0) w0 = 0.f;   // g[-1] = 0
    h2_t w; w.x = (_Float16)w0; w.y = (_Float16)w1;
    g_wtabh[p * WSTR + t] = w;
    if (t < WSTR - 32) {
        h2_t z; z.x = (_Float16)0.f; z.y = (_Float16)0.f;
        g_wtabh[p * WSTR + 32 + t] = z;
    }
}

__device__ __forceinline__ double plane_of(int i) {
    const double stepd = 50.0 / 31.0;
    return (i < 31) ? (double)i * stepd : 50.0;
}

// R6 structure exactly; ONLY change: row-dot accumulates in packed f16
// (v_pk_fma_f16, full-rate pipe hypothesis) instead of fdot2-f32 (measured
// ~4 cyc/inst: R6 VALU busy 120k cyc vs 65k predicted at 2 cyc/inst).
__launch_bounds__(256, 2)
__global__ void defocus_kernel(const float* __restrict__ img,
                               const float* __restrict__ coc,
                               float* __restrict__ out) {
    const int tx = threadIdx.x;            // 0..7
    const int ty = threadIdx.y;            // 0..31
    const int tid = ty * 8 + tx;
    const int tilex = blockIdx.x * TXO;
    const int tiley = blockIdx.y * TYO;
    const int b = blockIdx.z;

    __shared__ __align__(16) h2_t wtab[NP * WSTR];
    __shared__ __align__(16) h2_t tile[TROWS * TWORDS];

    for (int f = tid; f < NP * WSTR; f += 256) wtab[f] = g_wtabh[f];

    const int yo = tiley + ty;
    const int xo = tilex + tx * 4;

    // per-pixel bin index, exact double-precision boundary semantics
    const float4 cv = *(const float4*)&coc[((size_t)b * HH + yo) * WW + xo];
    const float cocf[4] = {cv.x, cv.y, cv.z, cv.w};
    int idx[4];
    #pragma unroll
    for (int j = 0; j < 4; ++j) {
        const double stepd = 50.0 / 31.0;
        double cd = (double)cocf[j];
        int i0 = (int)floor(cd / stepd + 0.5);
        i0 = min(max(i0, 0), 31);
        if (i0 > 0 && cd <= 0.5 * (plane_of(i0 - 1) + plane_of(i0))) {
            i0 -= 1;
        } else if (i0 < 31 && cd > 0.5 * (plane_of(i0) + plane_of(i0 + 1))) {
            i0 += 1;
        }
        idx[j] = i0;
    }

    __syncthreads();  // wtab staged

    // gather this thread's 4 weight rows into registers (one-time random-indexed reads)
    // even local col (j=0,2): phase A; odd (j=1,3): phase B (pre-shifted by one tap)
    h2_t wj[4][16];
    #pragma unroll
    for (int j = 0; j < 4; ++j) {
        const h2_t* wp = &wtab[idx[j] * WSTR + (j & 1) * 16];
        #pragma unroll
        for (int m = 0; m < 4; ++m) {
            h8_t v = *(const h8_t*)(wp + 4 * m);   // 16B aligned: WSTR%4==0
            #pragma unroll
            for (int q = 0; q < 4; ++q) {
                h2_t t; t.x = v[2 * q]; t.y = v[2 * q + 1];
                wj[j][4 * m + q] = t;
            }
        }
    }

    for (int c = 0; c < CC; ++c) {
        __syncthreads();  // previous channel's readers done
        const float* src = img + (size_t)(b * CC + c) * HH * WW;
        for (int f = tid; f < TROWS * TLW; f += 256) {
            int r = f >> 5;            // / TLW
            int w = f & 31;            // % TLW
            int gy = tiley - 15 + r;
            int gx = tilex - 15 + 2 * w;
            float v0 = 0.f, v1 = 0.f;
            if ((unsigned)gy < (unsigned)HH) {
                if ((unsigned)gx < (unsigned)WW) v0 = src[gy * WW + gx];
                if ((unsigned)(gx + 1) < (unsigned)WW) v1 = src[gy * WW + gx + 1];
            }
            h2_t pv; pv.x = (_Float16)v0; pv.y = (_Float16)v1;
            tile[r * TWORDS + w] = pv;
        }
        __syncthreads();

        float acc0 = 0.f, acc1 = 0.f, acc2 = 0.f, acc3 = 0.f;
        const h2_t* rowbase = &tile[ty * TWORDS + 2 * tx];
        #pragma unroll
        for (int dy = 0; dy < KC; ++dy) {
            const h2_t* rp = rowbase + dy * TWORDS;
            h2_t rw[18];
            #pragma unroll
            for (int m = 0; m < 9; ++m) {
                h4_t q = *(const h4_t*)(rp + 2 * m);   // ds_read_b64, conflict-free layout
                h2_t lo; lo.x = q[0]; lo.y = q[1];
                h2_t hi; hi.x = q[2]; hi.y = q[3];
                rw[2 * m]     = lo;
                rw[2 * m + 1] = hi;
            }
            // packed-f16 row dot: each half accumulates 16 products (sum <= 1)
            h2_t rs0 = (h2_t)0.f, rs1 = (h2_t)0.f, rs2 = (h2_t)0.f, rs3 = (h2_t)0.f;
            #pragma unroll
            for (int m = 0; m < 16; ++m) {
                rs0 += wj[0][m] * rw[m];       // v_pk_fma_f16
                rs1 += wj[1][m] * rw[m];
                rs2 += wj[2][m] * rw[m + 1];
                rs3 += wj[3][m] * rw[m + 1];
            }
            float r0 = (float)rs0.x + (float)rs0.y;
            float r1 = (float)rs1.x + (float)rs1.y;
            float r2 = (float)rs2.x + (float)rs2.y;
            float r3 = (float)rs3.x + (float)rs3.y;
            // column taps g[dy] from the same registers (dy unrolled -> static indices)
            float cw0, cw1, cw2, cw3;
            if ((dy & 1) == 0) {
                cw0 = (float)wj[0][dy >> 1].x;           // A: lo = g[dy]
                cw2 = (float)wj[2][dy >> 1].x;
                cw1 = (float)wj[1][dy >> 1].y;           // B: hi = g[dy]
                cw3 = (float)wj[3][dy >> 1].y;
            } else {
                cw0 = (float)wj[0][dy >> 1].y;           // A: hi = g[dy]
                cw2 = (float)wj[2][dy >> 1].y;
                cw1 = (float)wj[1][(dy + 1) >> 1].x;     // B: lo of next word = g[dy]
                cw3 = (float)wj[3][(dy + 1) >> 1].x;
            }
            acc0 += cw0 * r0;
            acc1 += cw1 * r1;
            acc2 += cw2 * r2;
            acc3 += cw3 * r3;
        }

        *(float4*)&out[((size_t)(b * CC + c) * HH + yo) * WW + xo] =
            make_float4(acc0, acc1, acc2, acc3);
    }
}

extern "C" void kernel_launch(void* const* d_in, const int* in_sizes, int n_in,
                              void* d_out, int out_size, void* d_ws, size_t ws_size,
                              hipStream_t stream) {
    const float* sharp = (const float*)d_in[0];
    const float* cocm  = (const float*)d_in[1];
    float* out = (float*)d_out;

    init_wtab_kernel<<<1, 1024, 0, stream>>>();
    dim3 grid(WW / TXO, HH / TYO, BB);
    dim3 block(8, 32, 1);
    defocus_kernel<<<grid, block, 0, stream>>>(sharp, cocm, out);
}

// Round 13
// 136.275 us; speedup vs baseline: 1.0701x; 1.0701x over previous
//
#include <hip/hip_runtime.h>
#include <math.h>

typedef _Float16 h2_t __attribute__((ext_vector_type(2)));
typedef _Float16 h4_t __attribute__((ext_vector_type(4)));
typedef _Float16 h8_t __attribute__((ext_vector_type(8)));

#define NP 32
#define KC 31
#define HH 512
#define WW 512
#define BB 4
#define CC 3

#define TXO 64        // 64-wide tile, 512-thread block: same inner loop, 2x outputs/block
#define TYO 32
#define NT 512        // threads per block
#define TROWS 62      // 32 outputs + 15 + 15 halo
#define TWORDS 48     // row stride in h2 words; holds the 94-half window (47 words) + 1 pad
#define WSTR 36       // weight table plane stride in half2-words

// Packed per-plane 1D Gaussian taps, phase A = (g[2m],g[2m+1]), phase B = (g[2m-1],g[2m]).
// HARD CONSTRAINTS (measured): weight gen in separate kernel (R4); grid z = BB
// (R4/R5: channel-split -> GB-scale scratch traffic); >128 VGPRs unobtainable ->
// 4 outputs/thread (R9/R10 spilled); R6 insert-style unpack (R11 shuffles -20%);
// fdot2 == pk_fma rate (R12) -> inner loop is final; this round only re-amortizes
// the prologue/staging over a 2x bigger block.
__device__ h2_t g_wtabh[NP * WSTR];

__global__ void init_wtab_kernel() {
    const int tid = threadIdx.x;          // 0..1023
    const int p = tid >> 5;               // plane
    const int t = tid & 31;               // padded tap position 0..31 (g[31]==0)
    const double stepd = 50.0 / 31.0;
    double coc = (p < 31) ? (double)p * stepd : 50.0;   // numpy linspace semantics
    float gt;
    if (coc < 0.5) {
        gt = (t == 15) ? 1.f : 0.f;       // identity plane (plane 0 only)
    } else {
        double sigma = coc / 2.355;
        int k = (int)(2.0 * coc + 1.0);   // trunc, matches python int()
        if ((k & 1) == 0) k += 1;
        if (k > KC) k = KC;
        int h = k / 2;
        int d = t - 15;
        float denom = (float)(2.0 * sigma * sigma);
        float v = (d >= -h && d <= h && t < KC) ? expf(-(float)(d * d) / denom) : 0.f;
        float s = v;
        #pragma unroll
        for (int off = 1; off < 32; off <<= 1) s += __shfl_xor(s, off, 32);
        gt = v / s;
    }
    const int m = t & 15;
    const int s0 = (t < 16) ? (2 * m) : ((2 * m - 1 < 0) ? 0 : 2 * m - 1);
    const int s1 = (t < 16) ? (2 * m + 1) : (2 * m);
    float w0 = __shfl(gt, s0, 32);
    float w1 = __shfl(gt, s1, 32);
    if (t >= 16 && (2 * m - 1) < 0) w0 = 0.f;   // g[-1] = 0
    h2_t w; w.x = (_Float16)w0; w.y = (_Float16)w1;
    g_wtabh[p * WSTR + t] = w;
    if (t < WSTR - 32) {
        h2_t z; z.x = (_Float16)0.f; z.y = (_Float16)0.f;
        g_wtabh[p * WSTR + 32 + t] = z;
    }
}

__device__ __forceinline__ double plane_of(int i) {
    const double stepd = 50.0 / 31.0;
    return (i < 31) ? (double)i * stepd : 50.0;
}

// (512,2): 256-VGPR cap, allocator lands at 128 -> 4 waves/SIMD, 2 blocks/CU
// (LDS 16.6 KB each). Inner dy-loop is R6 verbatim. Compute quarter-wave is now
// a full tx-row -> b64 reads hit all 32 banks exactly once (conflict-free).
__launch_bounds__(512, 2)
__global__ void defocus_kernel(const float* __restrict__ img,
                               const float* __restrict__ coc,
                               float* __restrict__ out) {
    const int tx = threadIdx.x;            // 0..15
    const int ty = threadIdx.y;            // 0..31
    const int tid = ty * 16 + tx;
    const int tilex = blockIdx.x * TXO;
    const int tiley = blockIdx.y * TYO;
    const int b = blockIdx.z;

    __shared__ __align__(16) h2_t wtab[NP * WSTR];
    __shared__ __align__(16) h2_t tile[TROWS * TWORDS];

    for (int f = tid; f < NP * WSTR; f += NT) wtab[f] = g_wtabh[f];

    const int yo = tiley + ty;
    const int xo = tilex + tx * 4;

    // per-pixel bin index, exact double-precision boundary semantics
    const float4 cv = *(const float4*)&coc[((size_t)b * HH + yo) * WW + xo];
    const float cocf[4] = {cv.x, cv.y, cv.z, cv.w};
    int idx[4];
    #pragma unroll
    for (int j = 0; j < 4; ++j) {
        const double stepd = 50.0 / 31.0;
        double cd = (double)cocf[j];
        int i0 = (int)floor(cd / stepd + 0.5);
        i0 = min(max(i0, 0), 31);
        if (i0 > 0 && cd <= 0.5 * (plane_of(i0 - 1) + plane_of(i0))) {
            i0 -= 1;
        } else if (i0 < 31 && cd > 0.5 * (plane_of(i0) + plane_of(i0 + 1))) {
            i0 += 1;
        }
        idx[j] = i0;
    }

    __syncthreads();  // wtab staged

    // gather this thread's 4 weight rows into registers (one-time random-indexed reads)
    // even local col (j=0,2): phase A; odd (j=1,3): phase B (pre-shifted by one tap)
    h2_t wj[4][16];
    #pragma unroll
    for (int j = 0; j < 4; ++j) {
        const h2_t* wp = &wtab[idx[j] * WSTR + (j & 1) * 16];
        #pragma unroll
        for (int m = 0; m < 4; ++m) {
            h8_t v = *(const h8_t*)(wp + 4 * m);   // 16B aligned: WSTR%4==0
            #pragma unroll
            for (int q = 0; q < 4; ++q) {
                h2_t t; t.x = v[2 * q]; t.y = v[2 * q + 1];
                wj[j][4 * m + q] = t;
            }
        }
    }

    for (int c = 0; c < CC; ++c) {
        __syncthreads();  // previous channel's readers done
        const float* src = img + (size_t)(b * CC + c) * HH * WW;
        // stage full 48-word rows (word 47 is pad: loaded into rw[17], never used
        // in the dots, OOB-guarded to 0)
        for (int f = tid; f < TROWS * TWORDS; f += NT) {
            int r = f / TWORDS;
            int w = f - r * TWORDS;
            int gy = tiley - 15 + r;
            int gx = tilex - 15 + 2 * w;
            float v0 = 0.f, v1 = 0.f;
            if ((unsigned)gy < (unsigned)HH) {
                if ((unsigned)gx < (unsigned)WW) v0 = src[gy * WW + gx];
                if ((unsigned)(gx + 1) < (unsigned)WW) v1 = src[gy * WW + gx + 1];
            }
            h2_t pv; pv.x = (_Float16)v0; pv.y = (_Float16)v1;
            tile[f] = pv;
        }
        __syncthreads();

        float acc0 = 0.f, acc1 = 0.f, acc2 = 0.f, acc3 = 0.f;
        const h2_t* rowbase = &tile[ty * TWORDS + 2 * tx];
        #pragma unroll
        for (int dy = 0; dy < KC; ++dy) {
            const h2_t* rp = rowbase + dy * TWORDS;
            h2_t rw[18];
            #pragma unroll
            for (int m = 0; m < 9; ++m) {
                h4_t q = *(const h4_t*)(rp + 2 * m);   // ds_read_b64, conflict-free
                h2_t lo; lo.x = q[0]; lo.y = q[1];
                h2_t hi; hi.x = q[2]; hi.y = q[3];
                rw[2 * m]     = lo;
                rw[2 * m + 1] = hi;
            }
            float rs0 = 0.f, rs1 = 0.f, rs2 = 0.f, rs3 = 0.f;
            #pragma unroll
            for (int m = 0; m < 16; ++m) {
                rs0 = __builtin_amdgcn_fdot2(wj[0][m], rw[m],     rs0, false);
                rs1 = __builtin_amdgcn_fdot2(wj[1][m], rw[m],     rs1, false);
                rs2 = __builtin_amdgcn_fdot2(wj[2][m], rw[m + 1], rs2, false);
                rs3 = __builtin_amdgcn_fdot2(wj[3][m], rw[m + 1], rs3, false);
            }
            // column taps g[dy] from the same registers (dy unrolled -> static indices)
            float cw0, cw1, cw2, cw3;
            if ((dy & 1) == 0) {
                cw0 = (float)wj[0][dy >> 1].x;           // A: lo = g[dy]
                cw2 = (float)wj[2][dy >> 1].x;
                cw1 = (float)wj[1][dy >> 1].y;           // B: hi = g[dy]
                cw3 = (float)wj[3][dy >> 1].y;
            } else {
                cw0 = (float)wj[0][dy >> 1].y;           // A: hi = g[dy]
                cw2 = (float)wj[2][dy >> 1].y;
                cw1 = (float)wj[1][(dy + 1) >> 1].x;     // B: lo of next word = g[dy]
                cw3 = (float)wj[3][(dy + 1) >> 1].x;
            }
            acc0 += cw0 * rs0;
            acc1 += cw1 * rs1;
            acc2 += cw2 * rs2;
            acc3 += cw3 * rs3;
        }

        *(float4*)&out[((size_t)(b * CC + c) * HH + yo) * WW + xo] =
            make_float4(acc0, acc1, acc2, acc3);
    }
}

extern "C" void kernel_launch(void* const* d_in, const int* in_sizes, int n_in,
                              void* d_out, int out_size, void* d_ws, size_t ws_size,
                              hipStream_t stream) {
    const float* sharp = (const float*)d_in[0];
    const float* cocm  = (const float*)d_in[1];
    float* out = (float*)d_out;

    init_wtab_kernel<<<1, 1024, 0, stream>>>();
    dim3 grid(WW / TXO, HH / TYO, BB);
    dim3 block(16, 32, 1);
    defocus_kernel<<<grid, block, 0, stream>>>(sharp, cocm, out);
}